// Round 3
// baseline (36.603 us; speedup 1.0000x reference)
//
#include <hip/hip_runtime.h>

#define D0 1024
#define D1 512
#define D2 256

typedef float f32x4 __attribute__((ext_vector_type(4)));

// Kernel 1: row sums of W0 (1024 rows x 512) and W1 (512 rows x 256).
// pred[b,i] = avg[b]*sum_j W[i,j] since avg is constant across features.
// One wave per row; float4 loads, f64 accumulate, store f32.
__global__ __launch_bounds__(64) void snn_rowsum(const float* __restrict__ W0,
                                                 const float* __restrict__ W1,
                                                 float* __restrict__ s) {
    const int row  = blockIdx.x;
    const int lane = threadIdx.x;
    const f32x4* base;
    int n4;
    if (row < D0) { base = (const f32x4*)(W0 + (size_t)row * D1);        n4 = D1 / 4; }
    else          { base = (const f32x4*)(W1 + (size_t)(row - D0) * D2); n4 = D2 / 4; }
    double acc = 0.0;
    for (int j = lane; j < n4; j += 64) {
        const f32x4 v = base[j];
        acc += ((double)v.x + (double)v.y) + ((double)v.z + (double)v.w);
    }
    #pragma unroll
    for (int off = 32; off >= 1; off >>= 1) acc += __shfl_xor(acc, off, 64);
    if (lane == 0) s[row] = (float)acc;
}

// Kernel 2: one wave per batch row. Per-layer state collapses to scalars
// (v, avg) per row because cur is a [B,1] broadcast and state starts at 0.
__global__ __launch_bounds__(256) void snn_main(const float* __restrict__ x,
                                                const float* __restrict__ s,
                                                const int* __restrict__ ts_ptr,
                                                float* __restrict__ out,
                                                int B) {
    const int lane = threadIdx.x & 63;
    const int wid  = threadIdx.x >> 6;
    const int b    = blockIdx.x * 4 + wid;
    if (b >= B) return;
    const int TS = *ts_ptr;

    // Vectorized loads. Lane l holds elements {4*(k*64+l) .. +3} of both x-row
    // and s — identical mapping for x and s0, so the pairwise |x - a0*s0| is
    // preserved (summation order differs from scalar version; sum is what matters).
    const f32x4* xv = (const f32x4*)(x + (size_t)b * D0);
    const f32x4* sv = (const f32x4*)s;
    f32x4 xk[4], s0k[4], s1k[2];
    #pragma unroll
    for (int k = 0; k < 4; ++k) xk[k] = __builtin_nontemporal_load(&xv[k * 64 + lane]);
    #pragma unroll
    for (int k = 0; k < 4; ++k) s0k[k] = sv[k * 64 + lane];
    #pragma unroll
    for (int k = 0; k < 2; ++k) s1k[k] = sv[D0 / 4 + k * 64 + lane];

    double v0 = 0.0, a0 = 0.0, v1 = 0.0, a1 = 0.0;

    for (int t = 0; t < TS; ++t) {
        const double tf = (double)t;
        const double a0_start = a0, a1_start = a1;

        // ----- layer 0: cur0 = 2 * mean_i |x_i - a0*s0_i| = S0/512 -----
        const float a0f = (float)a0;
        float p0 = 0.f, p1 = 0.f, p2 = 0.f, p3 = 0.f;
        #pragma unroll
        for (int k = 0; k < 4; ++k) {
            p0 += fabsf(fmaf(-a0f, s0k[k].x, xk[k].x));
            p1 += fabsf(fmaf(-a0f, s0k[k].y, xk[k].y));
            p2 += fabsf(fmaf(-a0f, s0k[k].z, xk[k].z));
            p3 += fabsf(fmaf(-a0f, s0k[k].w, xk[k].w));
        }
        float acc = (p0 + p1) + (p2 + p3);
        #pragma unroll
        for (int off = 32; off >= 1; off >>= 1) acc += __shfl_xor(acc, off, 64);
        const double cur0 = (double)acc * (1.0 / 512.0);
        v0 = 0.5 * v0 + cur0;
        const double sp0 = (v0 >= 1.0) ? 1.0 : 0.0;
        v0 = (v0 >= 1.0) ? 0.0 : v0;
        a0 = (a0 * tf + sp0) / (tf + 1.0);

        // ----- layer 1: cur1 = 2 * mean_i |a0_new - a1*s1_i| = S1/256 -----
        const float a1f  = (float)a1;
        const float a0nf = (float)a0;
        float q0 = 0.f, q1 = 0.f, q2 = 0.f, q3 = 0.f;
        #pragma unroll
        for (int k = 0; k < 2; ++k) {
            q0 += fabsf(fmaf(-a1f, s1k[k].x, a0nf));
            q1 += fabsf(fmaf(-a1f, s1k[k].y, a0nf));
            q2 += fabsf(fmaf(-a1f, s1k[k].z, a0nf));
            q3 += fabsf(fmaf(-a1f, s1k[k].w, a0nf));
        }
        float acc1 = (q0 + q1) + (q2 + q3);
        #pragma unroll
        for (int off = 32; off >= 1; off >>= 1) acc1 += __shfl_xor(acc1, off, 64);
        const double cur1 = (double)acc1 * (1.0 / 256.0);
        v1 = 0.5 * v1 + cur1;
        const double sp1 = (v1 >= 1.0) ? 1.0 : 0.0;
        v1 = (v1 >= 1.0) ? 0.0 : v1;
        a1 = (a1 * tf + sp1) / (tf + 1.0);

        // ----- exact fixed point: a0==a1==1, both spiked, v's reset to 0.
        // Every future step is bit-identical ((1*t+1)/(t+1)==1.0 exactly),
        // so stopping here is provably equivalent to running all TS steps.
        if (a0_start == 1.0 && sp0 == 1.0 && a1_start == 1.0 && sp1 == 1.0) break;
    }

    // Broadcast result across the 256 output features; one float4 per lane.
    const float r = (float)a1;
    f32x4* ov = (f32x4*)(out + (size_t)b * D2);
    f32x4 rv;
    rv.x = r; rv.y = r; rv.z = r; rv.w = r;
    __builtin_nontemporal_store(rv, &ov[lane]);
}

extern "C" void kernel_launch(void* const* d_in, const int* in_sizes, int n_in,
                              void* d_out, int out_size, void* d_ws, size_t ws_size,
                              hipStream_t stream) {
    const float* x  = (const float*)d_in[0];
    const float* W0 = (const float*)d_in[1];
    const float* W1 = (const float*)d_in[2];
    const int*   ts = (const int*)d_in[3];
    float* out = (float*)d_out;
    float* s   = (float*)d_ws;   // s[0..1024) = rowsum(W0), s[1024..1536) = rowsum(W1)
    const int B = in_sizes[0] / D0;

    snn_rowsum<<<D0 + D1, 64, 0, stream>>>(W0, W1, s);
    snn_main<<<(B + 3) / 4, 256, 0, stream>>>(x, s, ts, out, B);
}

// Round 4
// 35.813 us; speedup vs baseline: 1.0221x; 1.0221x over previous
//
#include <hip/hip_runtime.h>

#define D0 1024
#define D1 512
#define D2 256

typedef float f32x4 __attribute__((ext_vector_type(4)));

// Kernel 1: row sums of W0 (1024 rows x 512) and W1 (512 rows x 256).
// pred[b,i] = avg[b]*sum_j W[i,j] since avg is constant across features.
// 256-thread blocks, one wave per row (384 blocks total, cuts dispatch overhead).
__global__ __launch_bounds__(256) void snn_rowsum(const float* __restrict__ W0,
                                                  const float* __restrict__ W1,
                                                  float* __restrict__ s) {
    const int lane = threadIdx.x & 63;
    const int wid  = threadIdx.x >> 6;
    const int row  = blockIdx.x * 4 + wid;
    if (row >= D0 + D1) return;
    const f32x4* base;
    int n4;
    if (row < D0) { base = (const f32x4*)(W0 + (size_t)row * D1);        n4 = D1 / 4; }
    else          { base = (const f32x4*)(W1 + (size_t)(row - D0) * D2); n4 = D2 / 4; }
    double acc = 0.0;
    for (int j = lane; j < n4; j += 64) {
        const f32x4 v = base[j];
        acc += ((double)v.x + (double)v.y) + ((double)v.z + (double)v.w);
    }
    #pragma unroll
    for (int off = 32; off >= 1; off >>= 1) acc += __shfl_xor(acc, off, 64);
    if (lane == 0) s[row] = (float)acc;
}

// Kernel 2: 2 batch rows per wave (8 rows / 256-thread block). Per-layer state
// collapses to scalars (v, avg) per row because cur is a [B,1] broadcast and
// state starts at 0.
__global__ __launch_bounds__(256) void snn_main(const float* __restrict__ x,
                                                const float* __restrict__ s,
                                                const int* __restrict__ ts_ptr,
                                                float* __restrict__ out,
                                                int B) {
    const int lane = threadIdx.x & 63;
    const int wid  = threadIdx.x >> 6;
    const int b0   = blockIdx.x * 8 + wid * 2;
    if (b0 >= B) return;
    const bool has2 = (b0 + 1) < B;
    const int  b1   = has2 ? (b0 + 1) : b0;
    const int  TS   = *ts_ptr;

    // s first (L2/L3-resident after rowsum), then the two streaming x rows.
    const f32x4* sv = (const f32x4*)s;
    f32x4 s0k[4], s1k[2];
    #pragma unroll
    for (int k = 0; k < 4; ++k) s0k[k] = sv[k * 64 + lane];
    #pragma unroll
    for (int k = 0; k < 2; ++k) s1k[k] = sv[D0 / 4 + k * 64 + lane];

    const f32x4* xv0 = (const f32x4*)(x + (size_t)b0 * D0);
    const f32x4* xv1 = (const f32x4*)(x + (size_t)b1 * D0);
    f32x4 xa[4], xb[4];
    #pragma unroll
    for (int k = 0; k < 4; ++k) xa[k] = xv0[k * 64 + lane];
    #pragma unroll
    for (int k = 0; k < 4; ++k) xb[k] = xv1[k * 64 + lane];

    double v0a = 0.0, a0a = 0.0, v1a = 0.0, a1a = 0.0;
    double v0b = 0.0, a0b = 0.0, v1b = 0.0, a1b = 0.0;

    for (int t = 0; t < TS; ++t) {
        const double tf = (double)t;
        const double a0a_s = a0a, a1a_s = a1a, a0b_s = a0b, a1b_s = a1b;

        // ----- layer 0 both rows: cur0 = 2*mean|x - a0*s0| = S/512 -----
        const float fa = (float)a0a, fb = (float)a0b;
        float pa0 = 0.f, pa1 = 0.f, pa2 = 0.f, pa3 = 0.f;
        float pb0 = 0.f, pb1 = 0.f, pb2 = 0.f, pb3 = 0.f;
        #pragma unroll
        for (int k = 0; k < 4; ++k) {
            pa0 += fabsf(fmaf(-fa, s0k[k].x, xa[k].x));
            pa1 += fabsf(fmaf(-fa, s0k[k].y, xa[k].y));
            pa2 += fabsf(fmaf(-fa, s0k[k].z, xa[k].z));
            pa3 += fabsf(fmaf(-fa, s0k[k].w, xa[k].w));
            pb0 += fabsf(fmaf(-fb, s0k[k].x, xb[k].x));
            pb1 += fabsf(fmaf(-fb, s0k[k].y, xb[k].y));
            pb2 += fabsf(fmaf(-fb, s0k[k].z, xb[k].z));
            pb3 += fabsf(fmaf(-fb, s0k[k].w, xb[k].w));
        }
        float ra = (pa0 + pa1) + (pa2 + pa3);
        float rb = (pb0 + pb1) + (pb2 + pb3);
        #pragma unroll
        for (int off = 32; off >= 1; off >>= 1) {
            ra += __shfl_xor(ra, off, 64);
            rb += __shfl_xor(rb, off, 64);
        }
        v0a = 0.5 * v0a + (double)ra * (1.0 / 512.0);
        v0b = 0.5 * v0b + (double)rb * (1.0 / 512.0);
        const double sp0a = (v0a >= 1.0) ? 1.0 : 0.0;
        const double sp0b = (v0b >= 1.0) ? 1.0 : 0.0;
        v0a = (v0a >= 1.0) ? 0.0 : v0a;
        v0b = (v0b >= 1.0) ? 0.0 : v0b;
        a0a = (a0a * tf + sp0a) / (tf + 1.0);
        a0b = (a0b * tf + sp0b) / (tf + 1.0);

        // ----- layer 1 both rows: cur1 = 2*mean|a0_new - a1*s1| = S/256 -----
        const float ga = (float)a1a, gb = (float)a1b;
        const float na = (float)a0a, nb = (float)a0b;
        float qa0 = 0.f, qa1 = 0.f, qb0 = 0.f, qb1 = 0.f;
        #pragma unroll
        for (int k = 0; k < 2; ++k) {
            qa0 += fabsf(fmaf(-ga, s1k[k].x, na)) + fabsf(fmaf(-ga, s1k[k].z, na));
            qa1 += fabsf(fmaf(-ga, s1k[k].y, na)) + fabsf(fmaf(-ga, s1k[k].w, na));
            qb0 += fabsf(fmaf(-gb, s1k[k].x, nb)) + fabsf(fmaf(-gb, s1k[k].z, nb));
            qb1 += fabsf(fmaf(-gb, s1k[k].y, nb)) + fabsf(fmaf(-gb, s1k[k].w, nb));
        }
        float ta = qa0 + qa1;
        float tb = qb0 + qb1;
        #pragma unroll
        for (int off = 32; off >= 1; off >>= 1) {
            ta += __shfl_xor(ta, off, 64);
            tb += __shfl_xor(tb, off, 64);
        }
        v1a = 0.5 * v1a + (double)ta * (1.0 / 256.0);
        v1b = 0.5 * v1b + (double)tb * (1.0 / 256.0);
        const double sp1a = (v1a >= 1.0) ? 1.0 : 0.0;
        const double sp1b = (v1b >= 1.0) ? 1.0 : 0.0;
        v1a = (v1a >= 1.0) ? 0.0 : v1a;
        v1b = (v1b >= 1.0) ? 0.0 : v1b;
        a1a = (a1a * tf + sp1a) / (tf + 1.0);
        a1b = (a1b * tf + sp1b) / (tf + 1.0);

        // ----- exact fixed point per row (see proof): a==1 entering the step
        // + spike this step => every future step is bit-identical. Break when
        // both rows are saturated; extra iterations at the fixed point for an
        // already-saturated row are exact no-ops, so a shared break is safe.
        const bool doneA = (a0a_s == 1.0) && (sp0a == 1.0) && (a1a_s == 1.0) && (sp1a == 1.0);
        const bool doneB = (a0b_s == 1.0) && (sp0b == 1.0) && (a1b_s == 1.0) && (sp1b == 1.0);
        if (doneA && (doneB || !has2)) break;
    }

    // Broadcast result across the 256 output features; one f32x4 per lane.
    {
        const float r = (float)a1a;
        f32x4 rv; rv.x = r; rv.y = r; rv.z = r; rv.w = r;
        f32x4* ov = (f32x4*)(out + (size_t)b0 * D2);
        __builtin_nontemporal_store(rv, &ov[lane]);
    }
    if (has2) {
        const float r = (float)a1b;
        f32x4 rv; rv.x = r; rv.y = r; rv.z = r; rv.w = r;
        f32x4* ov = (f32x4*)(out + (size_t)b1 * D2);
        __builtin_nontemporal_store(rv, &ov[lane]);
    }
}

extern "C" void kernel_launch(void* const* d_in, const int* in_sizes, int n_in,
                              void* d_out, int out_size, void* d_ws, size_t ws_size,
                              hipStream_t stream) {
    const float* x  = (const float*)d_in[0];
    const float* W0 = (const float*)d_in[1];
    const float* W1 = (const float*)d_in[2];
    const int*   ts = (const int*)d_in[3];
    float* out = (float*)d_out;
    float* s   = (float*)d_ws;   // s[0..1024) = rowsum(W0), s[1024..1536) = rowsum(W1)
    const int B = in_sizes[0] / D0;

    snn_rowsum<<<(D0 + D1 + 3) / 4, 256, 0, stream>>>(W0, W1, s);
    snn_main<<<(B + 7) / 8, 256, 0, stream>>>(x, s, ts, out, B);
}